// Round 15
// baseline (137.814 us; speedup 1.0000x reference)
//
#include <hip/hip_runtime.h>
#include <hip/hip_bf16.h>
#include <hip/hip_fp16.h>
#include <math.h>

// ---------------------------------------------------------------------------
// OGCNConv, MFMA edition v12 (= v11 + gather/gate 2-stage node pipeline):
//   pack_zero -> count_gemm {count atomics || GEMM} -> scan1 -> scan3b(+dinv)
//   -> fill -> gather[0,nh) -> mix {gate[0,nh) || gather[nh,n)} -> gate[nh,n).
// ---------------------------------------------------------------------------

typedef __attribute__((ext_vector_type(8))) short bf16x8;
typedef __attribute__((ext_vector_type(4))) float f32x4;
typedef __attribute__((ext_vector_type(8))) unsigned short ushort8;

__device__ inline float b2f(unsigned short u) {
  return __uint_as_float(((unsigned)u) << 16);
}
__device__ inline unsigned short f2bf(float f) {
  __hip_bfloat16 b = __float2bfloat16(f);
  return *reinterpret_cast<unsigned short*>(&b);
}

// --- blocks [0,48): pack W to MFMA B-fragment order; rest: zero deg (int4).
__global__ __launch_bounds__(256) void pack_zero(const float* __restrict__ Wsl,
                                                 const float* __restrict__ W0,
                                                 const float* __restrict__ W1,
                                                 const float* __restrict__ Wg,
                                                 unsigned short* __restrict__ Wp3,
                                                 unsigned short* __restrict__ Wgp,
                                                 int4* __restrict__ deg4, int n4) {
  if (blockIdx.x < 48) {
    int tid = blockIdx.x * 256 + threadIdx.x;
    if (tid < 6144) {  // 3 mats, nct=8, nkf=4
      int z = tid / 2048, r = tid % 2048;
      int lane = r & 63, idx = r >> 6;
      int kf = idx & 3, ct = idx >> 2;
      const float* W = (z == 0) ? Wsl : (z == 1) ? W0 : W1;
      unsigned short* dst = Wp3 + (size_t)z * 16384 + (size_t)r * 8;
      int krow = kf * 32 + (lane >> 4) * 8;
      int ccol = ct * 16 + (lane & 15);
#pragma unroll
      for (int j = 0; j < 8; ++j) dst[j] = f2bf(W[(size_t)(krow + j) * 128 + ccol]);
    } else {  // Wg: nct=8, nkf=12
      int r = tid - 6144;
      int lane = r & 63, idx = r >> 6;
      int kf = idx % 12, ct = idx / 12;
      unsigned short* dst = Wgp + (size_t)r * 8;
      int krow = kf * 32 + (lane >> 4) * 8;
      int ccol = ct * 16 + (lane & 15);
#pragma unroll
      for (int j = 0; j < 8; ++j) dst[j] = f2bf(Wg[(size_t)(krow + j) * 128 + ccol]);
    }
  } else {
    int i = (blockIdx.x - 48) * 256 + threadIdx.x;
    if (i < n4) deg4[i] = make_int4(0, 0, 0, 0);
  }
}

// Fused: blocks [0,gb) = 3-way MFMA GEMM; blocks [gb,...) = deg count + rank.
__global__ __launch_bounds__(256) void count_gemm(
    const float* __restrict__ x, const unsigned short* __restrict__ Wp3,
    const float* __restrict__ bsl, unsigned short* __restrict__ hx,
    unsigned short* __restrict__ h0, unsigned short* __restrict__ h1,
    const int* __restrict__ col, const int* __restrict__ etype,
    int* __restrict__ deg, int* __restrict__ erank, int n, int E, int gb) {
  __shared__ unsigned short xs[64 * 136];                // 17 KB: A-tile / C-stage
  __shared__ __align__(16) unsigned short Bs[2][4096];   // 2 x 8 KB: W chunk dbuf
  int tid = threadIdx.x;
  if ((int)blockIdx.x >= gb) {  // ---- count branch ----
    int e = (blockIdx.x - gb) * 256 + tid;
    if (e >= E) return;
    int rk = atomicAdd(&deg[(size_t)etype[e] * n + col[e]], 1);
    erank[e] = rk;
    return;
  }
  // ---- GEMM branch ----
  int row0 = blockIdx.x * 64;
  {
    const float4* xg = (const float4*)(x + (size_t)row0 * 128);
    int maxv = (n - row0) * 32;
#pragma unroll
    for (int i = 0; i < 8; ++i) {
      int idx = tid + i * 256;
      float4 v = {0.f, 0.f, 0.f, 0.f};
      if (idx < maxv) v = xg[idx];
      int rr = idx >> 5, c4 = idx & 31;
      ushort4 u;
      u.x = f2bf(v.x);
      u.y = f2bf(v.y);
      u.z = f2bf(v.z);
      u.w = f2bf(v.w);
      *(ushort4*)&xs[rr * 136 + c4 * 4] = u;
    }
    int u = tid;
#pragma unroll
    for (int r = 0; r < 2; ++r, u += 256) {
      int ct = u >> 6, ll = u & 63;
      *(ushort8*)&Bs[0][u * 8] = *(const ushort8*)(Wp3 + ((size_t)(ct * 4) * 64 + ll) * 8);
    }
  }
  __syncthreads();
  int w = tid >> 6;
  int l = tid & 63;
  int q = l >> 4;
  int c = l & 15;
  bf16x8 af[4];
#pragma unroll
  for (int kf = 0; kf < 4; ++kf)
    af[kf] = *(const bf16x8*)&xs[(w * 16 + c) * 136 + kf * 32 + q * 8];
  __syncthreads();  // xs dead (af in regs); reuse as C-staging buffer

  f32x4 acc[8];
#pragma unroll
  for (int ct = 0; ct < 8; ++ct) acc[ct] = (f32x4){0.f, 0.f, 0.f, 0.f};
#pragma unroll
  for (int g = 0; g < 12; ++g) {
    int z = g >> 2, kf = g & 3;
    int cur = g & 1;
    if (g < 11) {
      int zn = (g + 1) >> 2, kfn = (g + 1) & 3;
      int u = tid;
#pragma unroll
      for (int r = 0; r < 2; ++r, u += 256) {
        int ct = u >> 6, ll = u & 63;
        *(ushort8*)&Bs[cur ^ 1][u * 8] = *(const ushort8*)(
            Wp3 + (size_t)zn * 16384 + ((size_t)(ct * 4 + kfn) * 64 + ll) * 8);
      }
    }
    bf16x8 a = af[kf];
#pragma unroll
    for (int ct = 0; ct < 8; ++ct)
      acc[ct] = __builtin_amdgcn_mfma_f32_16x16x32_bf16(
          a, *(const bf16x8*)&Bs[cur][(ct * 64 + l) * 8], acc[ct], 0, 0, 0);
    if (kf == 3) {
      unsigned short* h = (z == 0) ? hx : (z == 1) ? h0 : h1;
#pragma unroll
      for (int ct = 0; ct < 8; ++ct) {
        int fc = ct * 16 + c;
        float bias = (z == 0) ? bsl[fc] : 0.f;
#pragma unroll
        for (int i = 0; i < 4; ++i)
          xs[(w * 16 + q * 4 + i) * 136 + fc] = f2bf(acc[ct][i] + bias);
        acc[ct] = (f32x4){0.f, 0.f, 0.f, 0.f};
      }
      __syncthreads();
#pragma unroll
      for (int i = 0; i < 4; ++i) {
        int idx = tid + i * 256;
        int rr = idx >> 4, c8 = idx & 15;
        int gr = row0 + rr;
        if (gr < n)
          *(ushort8*)(h + (size_t)gr * 128 + c8 * 8) = *(const ushort8*)&xs[rr * 136 + c8 * 8];
      }
      __syncthreads();
    } else {
      __syncthreads();
    }
  }
}

__global__ __launch_bounds__(256) void scan1(const int* __restrict__ deg,
                                             int* __restrict__ partials, int n2) {
  int tid = threadIdx.x;
  int base = blockIdx.x * 2048 + tid * 8;
  int s = 0;
#pragma unroll
  for (int k = 0; k < 8; ++k) {
    int i = base + k;
    if (i < n2) s += deg[i];
  }
  __shared__ int sb[256];
  sb[tid] = s;
  __syncthreads();
  for (int o = 128; o; o >>= 1) {
    if (tid < o) sb[tid] += sb[tid + o];
    __syncthreads();
  }
  if (tid == 0) partials[blockIdx.x] = sb[0];
}

__global__ __launch_bounds__(256) void scan3b(const int* __restrict__ partials,
                                              const int* __restrict__ deg,
                                              int* __restrict__ row_start,
                                              float* __restrict__ dinv, int n2, int nb) {
  __shared__ int sb[256];
  __shared__ int ex[256];
  int tid = threadIdx.x;
  int pv = (tid < nb) ? partials[tid] : 0;
  sb[tid] = pv;
  __syncthreads();
  for (int o = 1; o < 256; o <<= 1) {
    int t = (tid >= o) ? sb[tid - o] : 0;
    __syncthreads();
    sb[tid] += t;
    __syncthreads();
  }
  ex[tid] = sb[tid] - pv;
  __syncthreads();
  int base = ex[blockIdx.x];
  __syncthreads();

  int bstart = blockIdx.x * 2048 + tid * 8;
  int v[8];
  int s = 0;
#pragma unroll
  for (int k = 0; k < 8; ++k) {
    int i = bstart + k;
    v[k] = (i < n2) ? deg[i] : 0;
    s += v[k];
    if (i < n2) dinv[i] = rsqrtf((float)v[k] + 1.0f);
  }
  sb[tid] = s;
  __syncthreads();
  for (int o = 1; o < 256; o <<= 1) {
    int t = (tid >= o) ? sb[tid - o] : 0;
    __syncthreads();
    sb[tid] += t;
    __syncthreads();
  }
  int run = base + (sb[tid] - s);
#pragma unroll
  for (int k = 0; k < 8; ++k) {
    int i = bstart + k;
    if (i < n2) {
      row_start[i] = run;
      run += v[k];
    }
  }
}

// Bucket fill, no atomics: pos = row_start[bucket] + erank[e].
__global__ __launch_bounds__(256) void fill_k(const int* __restrict__ row,
                                              const int* __restrict__ col,
                                              const int* __restrict__ etype,
                                              const int* __restrict__ erank,
                                              const int* __restrict__ row_start,
                                              const float* __restrict__ dinv,
                                              unsigned int* __restrict__ ebuf,
                                              int n, int E) {
  int e = blockIdx.x * 256 + threadIdx.x;
  if (e >= E) return;
  int r = row[e], c = col[e], t = etype[e];
  int b = t * n + c;
  float nrm = dinv[t * n + r] * dinv[b];
  int pos = row_start[b] + erank[e];
  unsigned int rec = (unsigned int)(r & 0xFFFF) |
                     ((unsigned int)__half_as_ushort(__float2half_rn(nrm)) << 16);
  ebuf[pos] = rec;
}

// --- gather body: 8 lanes/node, unroll-4, nodes [node_base, node_lim) ---
__device__ __forceinline__ void gather_body(
    int tid, int vbid, int t, int node_base, int node_lim,
    const unsigned short* __restrict__ h0, const unsigned short* __restrict__ h1,
    const unsigned int* __restrict__ ebuf, const int* __restrict__ row_start,
    const int* __restrict__ deg, const float* __restrict__ dinv,
    const float* __restrict__ b0, const float* __restrict__ b1,
    unsigned short* __restrict__ xn, unsigned short* __restrict__ xd, int n) {
  long long gid = (long long)vbid * 256 + tid;
  int node = node_base + (int)(gid >> 3);
  if (node >= node_lim) return;
  int sub = (int)(gid & 7);
  const ushort8* hp8 = (const ushort8*)(t ? h1 : h0);
  const float* bias = t ? b1 : b0;
  unsigned short* out = t ? xd : xn;
  const int* rs = row_start + (size_t)t * n;
  const int* dg = deg + (size_t)t * n;
  float di = dinv[(size_t)t * n + node];

  float accA[8], accB[8];
  float acc2A[8] = {0, 0, 0, 0, 0, 0, 0, 0}, acc2B[8] = {0, 0, 0, 0, 0, 0, 0, 0};
  {
    ushort8 sa = hp8[(size_t)node * 16 + sub * 2];
    ushort8 sbv = hp8[(size_t)node * 16 + sub * 2 + 1];
    float sl = di * di;
#pragma unroll
    for (int k = 0; k < 8; ++k) {
      accA[k] = fmaf(b2f(sa[k]), sl, bias[sub * 16 + k]);
      accB[k] = fmaf(b2f(sbv[k]), sl, bias[sub * 16 + 8 + k]);
    }
  }
  int s = rs[node];
  int e = s + dg[node];
  int j = s;
  for (; j + 3 < e; j += 4) {
    unsigned int r0 = ebuf[j], r1 = ebuf[j + 1], r2 = ebuf[j + 2], r3 = ebuf[j + 3];
    int i0 = (int)(r0 & 0xFFFFu), i1 = (int)(r1 & 0xFFFFu);
    int i2 = (int)(r2 & 0xFFFFu), i3 = (int)(r3 & 0xFFFFu);
    float n0 = __half2float(__ushort_as_half((unsigned short)(r0 >> 16)));
    float n1 = __half2float(__ushort_as_half((unsigned short)(r1 >> 16)));
    float n2 = __half2float(__ushort_as_half((unsigned short)(r2 >> 16)));
    float n3 = __half2float(__ushort_as_half((unsigned short)(r3 >> 16)));
    ushort8 v0a = hp8[(size_t)i0 * 16 + sub * 2];
    ushort8 v0b = hp8[(size_t)i0 * 16 + sub * 2 + 1];
    ushort8 v1a = hp8[(size_t)i1 * 16 + sub * 2];
    ushort8 v1b = hp8[(size_t)i1 * 16 + sub * 2 + 1];
    ushort8 v2a = hp8[(size_t)i2 * 16 + sub * 2];
    ushort8 v2b = hp8[(size_t)i2 * 16 + sub * 2 + 1];
    ushort8 v3a = hp8[(size_t)i3 * 16 + sub * 2];
    ushort8 v3b = hp8[(size_t)i3 * 16 + sub * 2 + 1];
#pragma unroll
    for (int k = 0; k < 8; ++k) {
      accA[k] = fmaf(b2f(v0a[k]), n0, accA[k]);
      accB[k] = fmaf(b2f(v0b[k]), n0, accB[k]);
      acc2A[k] = fmaf(b2f(v1a[k]), n1, acc2A[k]);
      acc2B[k] = fmaf(b2f(v1b[k]), n1, acc2B[k]);
      accA[k] = fmaf(b2f(v2a[k]), n2, accA[k]);
      accB[k] = fmaf(b2f(v2b[k]), n2, accB[k]);
      acc2A[k] = fmaf(b2f(v3a[k]), n3, acc2A[k]);
      acc2B[k] = fmaf(b2f(v3b[k]), n3, acc2B[k]);
    }
  }
  for (; j < e; ++j) {
    unsigned int r0 = ebuf[j];
    int i0 = (int)(r0 & 0xFFFFu);
    float n0 = __half2float(__ushort_as_half((unsigned short)(r0 >> 16)));
    ushort8 v0a = hp8[(size_t)i0 * 16 + sub * 2];
    ushort8 v0b = hp8[(size_t)i0 * 16 + sub * 2 + 1];
#pragma unroll
    for (int k = 0; k < 8; ++k) {
      accA[k] = fmaf(b2f(v0a[k]), n0, accA[k]);
      accB[k] = fmaf(b2f(v0b[k]), n0, accB[k]);
    }
  }
  ushort8 ua, ub;
#pragma unroll
  for (int k = 0; k < 8; ++k) {
    ua[k] = f2bf(accA[k] + acc2A[k]);
    ub[k] = f2bf(accB[k] + acc2B[k]);
  }
  ((ushort8*)out)[(size_t)node * 16 + sub * 2] = ua;
  ((ushort8*)out)[(size_t)node * 16 + sub * 2 + 1] = ub;
}

// --- gate body: 4 waves x 16 rows, rows [row_base + vbid*64, ...) ---
__device__ __forceinline__ void gate_body(
    int tid, int vbid, int row_base, int row_lim,
    const unsigned short* __restrict__ hx, const unsigned short* __restrict__ xn,
    const unsigned short* __restrict__ xd, const unsigned short* __restrict__ Wgp,
    const float* __restrict__ bg, float* __restrict__ out, int n,
    unsigned short (*Bs)[4096]) {
  int wv = tid >> 6;
  int l = tid & 63;
  int q = l >> 4;
  int c = l & 15;
  int row0 = row_base + vbid * 64 + wv * 16;
  int ar = row0 + c;
  if (ar > n - 1) ar = n - 1;  // clamp; outputs are guarded
  bf16x8 af[12];
  {
    const unsigned short* p0 = hx + (size_t)ar * 128 + q * 8;
    const unsigned short* p1 = xn + (size_t)ar * 128 + q * 8;
    const unsigned short* p2 = xd + (size_t)ar * 128 + q * 8;
#pragma unroll
    for (int k = 0; k < 4; ++k) {
      af[k] = *(const bf16x8*)(p0 + k * 32);
      af[4 + k] = *(const bf16x8*)(p1 + k * 32);
      af[8 + k] = *(const bf16x8*)(p2 + k * 32);
    }
  }
  {
    int u = tid;
#pragma unroll
    for (int r = 0; r < 2; ++r, u += 256) {
      int ct = u >> 6, ll = u & 63;
      *(ushort8*)&Bs[0][u * 8] = *(const ushort8*)(Wgp + ((size_t)(ct * 12) * 64 + ll) * 8);
    }
  }
  __syncthreads();
  f32x4 acc[8];
#pragma unroll
  for (int ct = 0; ct < 8; ++ct) acc[ct] = (f32x4){0.f, 0.f, 0.f, 0.f};
#pragma unroll
  for (int kf = 0; kf < 12; ++kf) {
    int cur = kf & 1;
    if (kf < 11) {
      int u = tid;
#pragma unroll
      for (int r = 0; r < 2; ++r, u += 256) {
        int ct = u >> 6, ll = u & 63;
        *(ushort8*)&Bs[cur ^ 1][u * 8] =
            *(const ushort8*)(Wgp + ((size_t)(ct * 12 + kf + 1) * 64 + ll) * 8);
      }
    }
    bf16x8 a = af[kf];
#pragma unroll
    for (int ct = 0; ct < 8; ++ct)
      acc[ct] = __builtin_amdgcn_mfma_f32_16x16x32_bf16(
          a, *(const bf16x8*)&Bs[cur][(ct * 64 + l) * 8], acc[ct], 0, 0, 0);
    if (kf < 11) __syncthreads();
  }
#pragma unroll
  for (int ct = 0; ct < 8; ++ct) {
    float bgv = bg[ct * 16 + c];
#pragma unroll
    for (int i = 0; i < 4; ++i) acc[ct][i] += bgv;
  }
#pragma unroll
  for (int i = 0; i < 4; ++i) {
    float m = acc[0][i];
#pragma unroll
    for (int ct = 1; ct < 8; ++ct) m = fmaxf(m, acc[ct][i]);
#pragma unroll
    for (int o = 1; o < 16; o <<= 1) m = fmaxf(m, __shfl_xor(m, o));
    float e[8];
    float s = 0.f;
#pragma unroll
    for (int ct = 0; ct < 8; ++ct) {
      e[ct] = __expf(acc[ct][i] - m);
      s += e[ct];
    }
#pragma unroll
    for (int o = 1; o < 16; o <<= 1) s += __shfl_xor(s, o);
    float inv = 1.0f / s;
    int gr = row0 + q * 4 + i;
    float run = 0.f;
#pragma unroll
    for (int ct = 0; ct < 8; ++ct) {
      float p = e[ct];
#pragma unroll
      for (int o = 1; o < 16; o <<= 1) {
        float t = __shfl_up(p, o);
        if (c >= o) p += t;
      }
      float T = __shfl(p, q * 16 + 15);
      float gat = (run + p) * inv;
      run += T;
      int f = ct * 16 + c;
      if (gr < row_lim) {
        size_t gb = (size_t)gr * 128;
        float xxv = b2f(hx[gb + f]);
        float xnv = b2f(xn[gb + f]);
        float xdv = b2f(xd[gb + 127 - f]);
        out[gb + f] = fmaf(xdv, gat, xxv + xnv);
      }
    }
  }
}

// Stage 1: gather nodes [0, nh), both relations (blockIdx.y = t).
__global__ __launch_bounds__(256) void gather_k(
    const unsigned short* __restrict__ h0, const unsigned short* __restrict__ h1,
    const unsigned int* __restrict__ ebuf, const int* __restrict__ row_start,
    const int* __restrict__ deg, const float* __restrict__ dinv,
    const float* __restrict__ b0, const float* __restrict__ b1,
    unsigned short* __restrict__ xn, unsigned short* __restrict__ xd,
    int node_base, int node_lim, int n) {
  gather_body(threadIdx.x, blockIdx.x, blockIdx.y, node_base, node_lim,
              h0, h1, ebuf, row_start, deg, dinv, b0, b1, xn, xd, n);
}

// Stage 2: blocks [0,gtb) = gate rows [0,nh); blocks [gtb,gtb+2*gab2) =
// gather nodes [nh,n) (first gab2 blocks t=0, next gab2 t=1).
__global__ __launch_bounds__(256) void mix_k(
    const unsigned short* __restrict__ hx, const unsigned short* __restrict__ h0,
    const unsigned short* __restrict__ h1, const unsigned int* __restrict__ ebuf,
    const int* __restrict__ row_start, const int* __restrict__ deg,
    const float* __restrict__ dinv, const float* __restrict__ b0,
    const float* __restrict__ b1, const unsigned short* __restrict__ Wgp,
    const float* __restrict__ bg, unsigned short* __restrict__ xn,
    unsigned short* __restrict__ xd, float* __restrict__ out,
    int gtb, int gab2, int nh, int n) {
  __shared__ __align__(16) unsigned short Bs[2][4096];
  if ((int)blockIdx.x < gtb) {
    gate_body(threadIdx.x, blockIdx.x, 0, nh, hx, xn, xd, Wgp, bg, out, n, Bs);
  } else {
    int b = blockIdx.x - gtb;
    int t = (b >= gab2) ? 1 : 0;
    int vb = t ? b - gab2 : b;
    gather_body(threadIdx.x, vb, t, nh, n, h0, h1, ebuf, row_start, deg, dinv,
                b0, b1, xn, xd, n);
  }
}

// Stage 3: gate rows [nh, n).
__global__ __launch_bounds__(256) void gate_k(
    const unsigned short* __restrict__ hx, const unsigned short* __restrict__ xn,
    const unsigned short* __restrict__ xd, const unsigned short* __restrict__ Wgp,
    const float* __restrict__ bg, float* __restrict__ out, int row_base, int n) {
  __shared__ __align__(16) unsigned short Bs[2][4096];
  gate_body(threadIdx.x, blockIdx.x, row_base, n, hx, xn, xd, Wgp, bg, out, n, Bs);
}

extern "C" void kernel_launch(void* const* d_in, const int* in_sizes, int n_in,
                              void* d_out, int out_size, void* d_ws, size_t ws_size,
                              hipStream_t stream) {
  const float* x = (const float*)d_in[0];
  const int* eidx = (const int*)d_in[1];
  const int* etype = (const int*)d_in[2];
  const float* Wsl = (const float*)d_in[3];
  const float* bsl = (const float*)d_in[4];
  const float* W0 = (const float*)d_in[5];
  const float* b0 = (const float*)d_in[6];
  const float* W1 = (const float*)d_in[7];
  const float* b1 = (const float*)d_in[8];
  const float* Wg = (const float*)d_in[9];
  const float* bg = (const float*)d_in[10];
  int n = in_sizes[0] / 128;
  int E = in_sizes[2];
  const int* row = eidx;
  const int* col = eidx + E;
  int n2 = 2 * n;

  char* w = (char*)d_ws;
  int* deg = (int*)w;             w += (size_t)n2 * 4;
  float* dinv = (float*)w;        w += (size_t)n2 * 4;
  int* row_start = (int*)w;       w += (size_t)n2 * 4;
  int* partials = (int*)w;        w += 1024;
  unsigned int* ebuf = (unsigned int*)w;  w += (size_t)E * 4;
  int* erank = (int*)w;           w += (size_t)E * 4;
  unsigned short* Wp3 = (unsigned short*)w;  w += 3 * 128 * 128 * 2;
  unsigned short* Wgp = (unsigned short*)w;  w += 384 * 128 * 2;
  unsigned short* hx = (unsigned short*)w;   w += (size_t)n * 128 * 2;
  unsigned short* h0 = (unsigned short*)w;   w += (size_t)n * 128 * 2;
  unsigned short* h1 = (unsigned short*)w;   w += (size_t)n * 128 * 2;
  unsigned short* xn = (unsigned short*)w;   w += (size_t)n * 128 * 2;
  unsigned short* xd = (unsigned short*)w;
  float* out = (float*)d_out;

  int n4 = n2 / 4;
  int zb = (n4 + 255) / 256;
  pack_zero<<<48 + zb, 256, 0, stream>>>(Wsl, W0, W1, Wg, Wp3, Wgp, (int4*)deg, n4);

  int cd_blocks = (E + 255) / 256;
  int gemm_blocks = (n + 63) / 64;
  count_gemm<<<gemm_blocks + cd_blocks, 256, 0, stream>>>(
      x, Wp3, bsl, hx, h0, h1, col, etype, deg, erank, n, E, gemm_blocks);

  int nb = (n2 + 2047) / 2048;
  scan1<<<nb, 256, 0, stream>>>(deg, partials, n2);
  scan3b<<<nb, 256, 0, stream>>>(partials, deg, row_start, dinv, n2, nb);

  fill_k<<<cd_blocks, 256, 0, stream>>>(row, col, etype, erank, row_start, dinv,
                                        ebuf, n, E);

  // 2-stage gather/gate pipeline over nodes
  int nh = ((n / 2 + 63) / 64) * 64;
  if (nh > n) nh = n;
  int ga1 = (int)(((long long)nh * 8 + 255) / 256);
  gather_k<<<dim3(ga1, 2), 256, 0, stream>>>(h0, h1, ebuf, row_start, deg, dinv,
                                             b0, b1, xn, xd, 0, nh, n);
  int gtb = nh / 64;
  int gab2 = (int)(((long long)(n - nh) * 8 + 255) / 256);
  mix_k<<<gtb + 2 * gab2, 256, 0, stream>>>(hx, h0, h1, ebuf, row_start, deg, dinv,
                                            b0, b1, Wgp, bg, xn, xd, out,
                                            gtb, gab2, nh, n);
  int g2 = (n - nh + 63) / 64;
  if (g2 > 0)
    gate_k<<<g2, 256, 0, stream>>>(hx, xn, xd, Wgp, bg, out, nh, n);
}

// Round 16
// 123.670 us; speedup vs baseline: 1.1144x; 1.1144x over previous
//
#include <hip/hip_runtime.h>
#include <hip/hip_bf16.h>
#include <hip/hip_fp16.h>
#include <math.h>

// ---------------------------------------------------------------------------
// OGCNConv, MFMA edition v11 (best verified: 124.5 us @ R14):
//   pack_zero {W pack + deg zero} -> count_gemm {deg count+rank atomics ||
//   3-way MFMA GEMM} -> scan1 -> scan3b(+dinv) -> fill (no atomics) ->
//   gather2 -> gate_combine.
// R15's gather/gate pipeline split regressed (latency-bound gather needs the
// full-width grid); reverted.
// ---------------------------------------------------------------------------

typedef __attribute__((ext_vector_type(8))) short bf16x8;
typedef __attribute__((ext_vector_type(4))) float f32x4;
typedef __attribute__((ext_vector_type(8))) unsigned short ushort8;

__device__ inline float b2f(unsigned short u) {
  return __uint_as_float(((unsigned)u) << 16);
}
__device__ inline unsigned short f2bf(float f) {
  __hip_bfloat16 b = __float2bfloat16(f);
  return *reinterpret_cast<unsigned short*>(&b);
}

// --- blocks [0,48): pack W to MFMA B-fragment order; rest: zero deg (int4).
__global__ __launch_bounds__(256) void pack_zero(const float* __restrict__ Wsl,
                                                 const float* __restrict__ W0,
                                                 const float* __restrict__ W1,
                                                 const float* __restrict__ Wg,
                                                 unsigned short* __restrict__ Wp3,
                                                 unsigned short* __restrict__ Wgp,
                                                 int4* __restrict__ deg4, int n4) {
  if (blockIdx.x < 48) {
    int tid = blockIdx.x * 256 + threadIdx.x;
    if (tid < 6144) {  // 3 mats, nct=8, nkf=4
      int z = tid / 2048, r = tid % 2048;
      int lane = r & 63, idx = r >> 6;
      int kf = idx & 3, ct = idx >> 2;
      const float* W = (z == 0) ? Wsl : (z == 1) ? W0 : W1;
      unsigned short* dst = Wp3 + (size_t)z * 16384 + (size_t)r * 8;
      int krow = kf * 32 + (lane >> 4) * 8;
      int ccol = ct * 16 + (lane & 15);
#pragma unroll
      for (int j = 0; j < 8; ++j) dst[j] = f2bf(W[(size_t)(krow + j) * 128 + ccol]);
    } else {  // Wg: nct=8, nkf=12
      int r = tid - 6144;
      int lane = r & 63, idx = r >> 6;
      int kf = idx % 12, ct = idx / 12;
      unsigned short* dst = Wgp + (size_t)r * 8;
      int krow = kf * 32 + (lane >> 4) * 8;
      int ccol = ct * 16 + (lane & 15);
#pragma unroll
      for (int j = 0; j < 8; ++j) dst[j] = f2bf(Wg[(size_t)(krow + j) * 128 + ccol]);
    }
  } else {
    int i = (blockIdx.x - 48) * 256 + threadIdx.x;
    if (i < n4) deg4[i] = make_int4(0, 0, 0, 0);
  }
}

// Fused: blocks [0,gb) = 3-way MFMA GEMM (W staged in per-kf 8KB LDS chunks,
//        double-buffered; LDS-staged coalesced C);
//        blocks [gb,...) = deg count + edge rank (atomic storm, hidden under
//        the GEMM's compute).
__global__ __launch_bounds__(256) void count_gemm(
    const float* __restrict__ x, const unsigned short* __restrict__ Wp3,
    const float* __restrict__ bsl, unsigned short* __restrict__ hx,
    unsigned short* __restrict__ h0, unsigned short* __restrict__ h1,
    const int* __restrict__ col, const int* __restrict__ etype,
    int* __restrict__ deg, int* __restrict__ erank, int n, int E, int gb) {
  __shared__ unsigned short xs[64 * 136];                // 17 KB: A-tile / C-stage
  __shared__ __align__(16) unsigned short Bs[2][4096];   // 2 x 8 KB: W chunk dbuf
  int tid = threadIdx.x;
  if ((int)blockIdx.x >= gb) {  // ---- count branch ----
    int e = (blockIdx.x - gb) * 256 + tid;
    if (e >= E) return;
    int rk = atomicAdd(&deg[(size_t)etype[e] * n + col[e]], 1);
    erank[e] = rk;
    return;
  }
  // ---- GEMM branch ----
  int row0 = blockIdx.x * 64;
  {
    const float4* xg = (const float4*)(x + (size_t)row0 * 128);
    int maxv = (n - row0) * 32;
#pragma unroll
    for (int i = 0; i < 8; ++i) {
      int idx = tid + i * 256;
      float4 v = {0.f, 0.f, 0.f, 0.f};
      if (idx < maxv) v = xg[idx];
      int rr = idx >> 5, c4 = idx & 31;
      ushort4 u;
      u.x = f2bf(v.x);
      u.y = f2bf(v.y);
      u.z = f2bf(v.z);
      u.w = f2bf(v.w);
      *(ushort4*)&xs[rr * 136 + c4 * 4] = u;
    }
    // stage chunk g=0 (z=0, kf=0)
    int u = tid;
#pragma unroll
    for (int r = 0; r < 2; ++r, u += 256) {
      int ct = u >> 6, ll = u & 63;
      *(ushort8*)&Bs[0][u * 8] = *(const ushort8*)(Wp3 + ((size_t)(ct * 4) * 64 + ll) * 8);
    }
  }
  __syncthreads();
  int w = tid >> 6;
  int l = tid & 63;
  int q = l >> 4;
  int c = l & 15;
  bf16x8 af[4];
#pragma unroll
  for (int kf = 0; kf < 4; ++kf)
    af[kf] = *(const bf16x8*)&xs[(w * 16 + c) * 136 + kf * 32 + q * 8];
  __syncthreads();  // xs dead (af in regs); reuse as C-staging buffer

  f32x4 acc[8];
#pragma unroll
  for (int ct = 0; ct < 8; ++ct) acc[ct] = (f32x4){0.f, 0.f, 0.f, 0.f};
#pragma unroll
  for (int g = 0; g < 12; ++g) {
    int z = g >> 2, kf = g & 3;
    int cur = g & 1;
    if (g < 11) {  // stage next chunk into other buffer
      int zn = (g + 1) >> 2, kfn = (g + 1) & 3;
      int u = tid;
#pragma unroll
      for (int r = 0; r < 2; ++r, u += 256) {
        int ct = u >> 6, ll = u & 63;
        *(ushort8*)&Bs[cur ^ 1][u * 8] = *(const ushort8*)(
            Wp3 + (size_t)zn * 16384 + ((size_t)(ct * 4 + kfn) * 64 + ll) * 8);
      }
    }
    bf16x8 a = af[kf];
#pragma unroll
    for (int ct = 0; ct < 8; ++ct)
      acc[ct] = __builtin_amdgcn_mfma_f32_16x16x32_bf16(
          a, *(const bf16x8*)&Bs[cur][(ct * 64 + l) * 8], acc[ct], 0, 0, 0);
    if (kf == 3) {
      unsigned short* h = (z == 0) ? hx : (z == 1) ? h0 : h1;
#pragma unroll
      for (int ct = 0; ct < 8; ++ct) {
        int fc = ct * 16 + c;
        float bias = (z == 0) ? bsl[fc] : 0.f;
#pragma unroll
        for (int i = 0; i < 4; ++i)
          xs[(w * 16 + q * 4 + i) * 136 + fc] = f2bf(acc[ct][i] + bias);
        acc[ct] = (f32x4){0.f, 0.f, 0.f, 0.f};
      }
      __syncthreads();  // C visible; next-chunk staging complete
#pragma unroll
      for (int i = 0; i < 4; ++i) {
        int idx = tid + i * 256;
        int rr = idx >> 4, c8 = idx & 15;
        int gr = row0 + rr;
        if (gr < n)
          *(ushort8*)(h + (size_t)gr * 128 + c8 * 8) = *(const ushort8*)&xs[rr * 136 + c8 * 8];
      }
      __syncthreads();  // xs free; safe to overwrite Bs[cur] next g
    } else {
      __syncthreads();  // staged chunk visible; Bs[cur] reads done
    }
  }
}

// --- per-2048-chunk partial sums of deg.
__global__ __launch_bounds__(256) void scan1(const int* __restrict__ deg,
                                             int* __restrict__ partials, int n2) {
  int tid = threadIdx.x;
  int base = blockIdx.x * 2048 + tid * 8;
  int s = 0;
#pragma unroll
  for (int k = 0; k < 8; ++k) {
    int i = base + k;
    if (i < n2) s += deg[i];
  }
  __shared__ int sb[256];
  sb[tid] = s;
  __syncthreads();
  for (int o = 128; o; o >>= 1) {
    if (tid < o) sb[tid] += sb[tid + o];
    __syncthreads();
  }
  if (tid == 0) partials[blockIdx.x] = sb[0];
}

// Exclusive scan (redundant top-level) + dinv computed in the same pass.
__global__ __launch_bounds__(256) void scan3b(const int* __restrict__ partials,
                                              const int* __restrict__ deg,
                                              int* __restrict__ row_start,
                                              float* __restrict__ dinv, int n2, int nb) {
  __shared__ int sb[256];
  __shared__ int ex[256];
  int tid = threadIdx.x;
  int pv = (tid < nb) ? partials[tid] : 0;
  sb[tid] = pv;
  __syncthreads();
  for (int o = 1; o < 256; o <<= 1) {
    int t = (tid >= o) ? sb[tid - o] : 0;
    __syncthreads();
    sb[tid] += t;
    __syncthreads();
  }
  ex[tid] = sb[tid] - pv;
  __syncthreads();
  int base = ex[blockIdx.x];
  __syncthreads();

  int bstart = blockIdx.x * 2048 + tid * 8;
  int v[8];
  int s = 0;
#pragma unroll
  for (int k = 0; k < 8; ++k) {
    int i = bstart + k;
    v[k] = (i < n2) ? deg[i] : 0;
    s += v[k];
    if (i < n2) dinv[i] = rsqrtf((float)v[k] + 1.0f);
  }
  sb[tid] = s;
  __syncthreads();
  for (int o = 1; o < 256; o <<= 1) {
    int t = (tid >= o) ? sb[tid - o] : 0;
    __syncthreads();
    sb[tid] += t;
    __syncthreads();
  }
  int run = base + (sb[tid] - s);
#pragma unroll
  for (int k = 0; k < 8; ++k) {
    int i = bstart + k;
    if (i < n2) {
      row_start[i] = run;
      run += v[k];
    }
  }
}

// Bucket fill, no atomics: pos = row_start[bucket] + erank[e].
__global__ __launch_bounds__(256) void fill_k(const int* __restrict__ row,
                                              const int* __restrict__ col,
                                              const int* __restrict__ etype,
                                              const int* __restrict__ erank,
                                              const int* __restrict__ row_start,
                                              const float* __restrict__ dinv,
                                              unsigned int* __restrict__ ebuf,
                                              int n, int E) {
  int e = blockIdx.x * 256 + threadIdx.x;
  if (e >= E) return;
  int r = row[e], c = col[e], t = etype[e];
  int b = t * n + c;
  float nrm = dinv[t * n + r] * dinv[b];
  int pos = row_start[b] + erank[e];
  unsigned int rec = (unsigned int)(r & 0xFFFF) |
                     ((unsigned int)__half_as_ushort(__float2half_rn(nrm)) << 16);
  ebuf[pos] = rec;
}

// Merged CSR gather: 8 lanes/node (2x ushort8 per lane), unroll-4.
__global__ __launch_bounds__(256) void gather2(const unsigned short* __restrict__ h0,
                                               const unsigned short* __restrict__ h1,
                                               const unsigned int* __restrict__ ebuf,
                                               const int* __restrict__ row_start,
                                               const int* __restrict__ deg,
                                               const float* __restrict__ dinv,
                                               const float* __restrict__ b0,
                                               const float* __restrict__ b1,
                                               unsigned short* __restrict__ xn,
                                               unsigned short* __restrict__ xd, int n) {
  int t = blockIdx.y;
  long long gid = (long long)blockIdx.x * 256 + threadIdx.x;
  int node = (int)(gid >> 3);
  if (node >= n) return;
  int sub = (int)(gid & 7);
  const ushort8* hp8 = (const ushort8*)(t ? h1 : h0);
  const float* bias = t ? b1 : b0;
  unsigned short* out = t ? xd : xn;
  const int* rs = row_start + (size_t)t * n;
  const int* dg = deg + (size_t)t * n;
  float di = dinv[(size_t)t * n + node];

  float accA[8], accB[8];
  float acc2A[8] = {0, 0, 0, 0, 0, 0, 0, 0}, acc2B[8] = {0, 0, 0, 0, 0, 0, 0, 0};
  {
    ushort8 sa = hp8[(size_t)node * 16 + sub * 2];
    ushort8 sbv = hp8[(size_t)node * 16 + sub * 2 + 1];
    float sl = di * di;
#pragma unroll
    for (int k = 0; k < 8; ++k) {
      accA[k] = fmaf(b2f(sa[k]), sl, bias[sub * 16 + k]);
      accB[k] = fmaf(b2f(sbv[k]), sl, bias[sub * 16 + 8 + k]);
    }
  }
  int s = rs[node];
  int e = s + dg[node];
  int j = s;
  for (; j + 3 < e; j += 4) {
    unsigned int r0 = ebuf[j], r1 = ebuf[j + 1], r2 = ebuf[j + 2], r3 = ebuf[j + 3];
    int i0 = (int)(r0 & 0xFFFFu), i1 = (int)(r1 & 0xFFFFu);
    int i2 = (int)(r2 & 0xFFFFu), i3 = (int)(r3 & 0xFFFFu);
    float n0 = __half2float(__ushort_as_half((unsigned short)(r0 >> 16)));
    float n1 = __half2float(__ushort_as_half((unsigned short)(r1 >> 16)));
    float n2 = __half2float(__ushort_as_half((unsigned short)(r2 >> 16)));
    float n3 = __half2float(__ushort_as_half((unsigned short)(r3 >> 16)));
    ushort8 v0a = hp8[(size_t)i0 * 16 + sub * 2];
    ushort8 v0b = hp8[(size_t)i0 * 16 + sub * 2 + 1];
    ushort8 v1a = hp8[(size_t)i1 * 16 + sub * 2];
    ushort8 v1b = hp8[(size_t)i1 * 16 + sub * 2 + 1];
    ushort8 v2a = hp8[(size_t)i2 * 16 + sub * 2];
    ushort8 v2b = hp8[(size_t)i2 * 16 + sub * 2 + 1];
    ushort8 v3a = hp8[(size_t)i3 * 16 + sub * 2];
    ushort8 v3b = hp8[(size_t)i3 * 16 + sub * 2 + 1];
#pragma unroll
    for (int k = 0; k < 8; ++k) {
      accA[k] = fmaf(b2f(v0a[k]), n0, accA[k]);
      accB[k] = fmaf(b2f(v0b[k]), n0, accB[k]);
      acc2A[k] = fmaf(b2f(v1a[k]), n1, acc2A[k]);
      acc2B[k] = fmaf(b2f(v1b[k]), n1, acc2B[k]);
      accA[k] = fmaf(b2f(v2a[k]), n2, accA[k]);
      accB[k] = fmaf(b2f(v2b[k]), n2, accB[k]);
      acc2A[k] = fmaf(b2f(v3a[k]), n3, acc2A[k]);
      acc2B[k] = fmaf(b2f(v3b[k]), n3, acc2B[k]);
    }
  }
  for (; j < e; ++j) {
    unsigned int r0 = ebuf[j];
    int i0 = (int)(r0 & 0xFFFFu);
    float n0 = __half2float(__ushort_as_half((unsigned short)(r0 >> 16)));
    ushort8 v0a = hp8[(size_t)i0 * 16 + sub * 2];
    ushort8 v0b = hp8[(size_t)i0 * 16 + sub * 2 + 1];
#pragma unroll
    for (int k = 0; k < 8; ++k) {
      accA[k] = fmaf(b2f(v0a[k]), n0, accA[k]);
      accB[k] = fmaf(b2f(v0b[k]), n0, accB[k]);
    }
  }
  ushort8 ua, ub;
#pragma unroll
  for (int k = 0; k < 8; ++k) {
    ua[k] = f2bf(accA[k] + acc2A[k]);
    ub[k] = f2bf(accB[k] + acc2B[k]);
  }
  ((ushort8*)out)[(size_t)node * 16 + sub * 2] = ua;
  ((ushort8*)out)[(size_t)node * 16 + sub * 2 + 1] = ub;
}

// Gate GEMM (K=384) + softmax + cumsum + combine. 4 waves x 16 rows = 64 rows
// per block. B staged in LDS 8KB chunks (one per kf), double-buffered.
__global__ __launch_bounds__(256) void gate_combine(
    const unsigned short* __restrict__ hx, const unsigned short* __restrict__ xn,
    const unsigned short* __restrict__ xd, const unsigned short* __restrict__ Wgp,
    const float* __restrict__ bg, float* __restrict__ out, int n) {
  __shared__ __align__(16) unsigned short Bs[2][4096];  // 8KB per buffer
  int tid = threadIdx.x;
  int wv = tid >> 6;
  int l = tid & 63;
  int q = l >> 4;
  int c = l & 15;
  int row0 = blockIdx.x * 64 + wv * 16;
  int ar = row0 + c;
  if (ar > n - 1) ar = n - 1;  // clamp; outputs are guarded
  bf16x8 af[12];
  {
    const unsigned short* p0 = hx + (size_t)ar * 128 + q * 8;
    const unsigned short* p1 = xn + (size_t)ar * 128 + q * 8;
    const unsigned short* p2 = xd + (size_t)ar * 128 + q * 8;
#pragma unroll
    for (int k = 0; k < 4; ++k) {
      af[k] = *(const bf16x8*)(p0 + k * 32);
      af[4 + k] = *(const bf16x8*)(p1 + k * 32);
      af[8 + k] = *(const bf16x8*)(p2 + k * 32);
    }
  }
  {
    int u = tid;
#pragma unroll
    for (int r = 0; r < 2; ++r, u += 256) {
      int ct = u >> 6, ll = u & 63;
      *(ushort8*)&Bs[0][u * 8] = *(const ushort8*)(Wgp + ((size_t)(ct * 12) * 64 + ll) * 8);
    }
  }
  __syncthreads();
  f32x4 acc[8];
#pragma unroll
  for (int ct = 0; ct < 8; ++ct) acc[ct] = (f32x4){0.f, 0.f, 0.f, 0.f};
#pragma unroll
  for (int kf = 0; kf < 12; ++kf) {
    int cur = kf & 1;
    if (kf < 11) {
      int u = tid;
#pragma unroll
      for (int r = 0; r < 2; ++r, u += 256) {
        int ct = u >> 6, ll = u & 63;
        *(ushort8*)&Bs[cur ^ 1][u * 8] =
            *(const ushort8*)(Wgp + ((size_t)(ct * 12 + kf + 1) * 64 + ll) * 8);
      }
    }
    bf16x8 a = af[kf];
#pragma unroll
    for (int ct = 0; ct < 8; ++ct)
      acc[ct] = __builtin_amdgcn_mfma_f32_16x16x32_bf16(
          a, *(const bf16x8*)&Bs[cur][(ct * 64 + l) * 8], acc[ct], 0, 0, 0);
    if (kf < 11) __syncthreads();
  }
#pragma unroll
  for (int ct = 0; ct < 8; ++ct) {
    float bgv = bg[ct * 16 + c];
#pragma unroll
    for (int i = 0; i < 4; ++i) acc[ct][i] += bgv;
  }
#pragma unroll
  for (int i = 0; i < 4; ++i) {
    float m = acc[0][i];
#pragma unroll
    for (int ct = 1; ct < 8; ++ct) m = fmaxf(m, acc[ct][i]);
#pragma unroll
    for (int o = 1; o < 16; o <<= 1) m = fmaxf(m, __shfl_xor(m, o));
    float e[8];
    float s = 0.f;
#pragma unroll
    for (int ct = 0; ct < 8; ++ct) {
      e[ct] = __expf(acc[ct][i] - m);
      s += e[ct];
    }
#pragma unroll
    for (int o = 1; o < 16; o <<= 1) s += __shfl_xor(s, o);
    float inv = 1.0f / s;
    int gr = row0 + q * 4 + i;
    float run = 0.f;
#pragma unroll
    for (int ct = 0; ct < 8; ++ct) {
      float p = e[ct];
#pragma unroll
      for (int o = 1; o < 16; o <<= 1) {
        float t = __shfl_up(p, o);
        if (c >= o) p += t;
      }
      float T = __shfl(p, q * 16 + 15);
      float gat = (run + p) * inv;
      run += T;
      int f = ct * 16 + c;
      if (gr < n) {
        size_t gb = (size_t)gr * 128;
        float xxv = b2f(hx[gb + f]);
        float xnv = b2f(xn[gb + f]);
        float xdv = b2f(xd[gb + 127 - f]);
        out[gb + f] = fmaf(xdv, gat, xxv + xnv);
      }
    }
  }
}

extern "C" void kernel_launch(void* const* d_in, const int* in_sizes, int n_in,
                              void* d_out, int out_size, void* d_ws, size_t ws_size,
                              hipStream_t stream) {
  const float* x = (const float*)d_in[0];
  const int* eidx = (const int*)d_in[1];
  const int* etype = (const int*)d_in[2];
  const float* Wsl = (const float*)d_in[3];
  const float* bsl = (const float*)d_in[4];
  const float* W0 = (const float*)d_in[5];
  const float* b0 = (const float*)d_in[6];
  const float* W1 = (const float*)d_in[7];
  const float* b1 = (const float*)d_in[8];
  const float* Wg = (const float*)d_in[9];
  const float* bg = (const float*)d_in[10];
  int n = in_sizes[0] / 128;
  int E = in_sizes[2];
  const int* row = eidx;
  const int* col = eidx + E;
  int n2 = 2 * n;

  char* w = (char*)d_ws;
  int* deg = (int*)w;             w += (size_t)n2 * 4;
  float* dinv = (float*)w;        w += (size_t)n2 * 4;
  int* row_start = (int*)w;       w += (size_t)n2 * 4;
  int* partials = (int*)w;        w += 1024;
  unsigned int* ebuf = (unsigned int*)w;  w += (size_t)E * 4;
  int* erank = (int*)w;           w += (size_t)E * 4;
  unsigned short* Wp3 = (unsigned short*)w;  w += 3 * 128 * 128 * 2;
  unsigned short* Wgp = (unsigned short*)w;  w += 384 * 128 * 2;
  unsigned short* hx = (unsigned short*)w;   w += (size_t)n * 128 * 2;
  unsigned short* h0 = (unsigned short*)w;   w += (size_t)n * 128 * 2;
  unsigned short* h1 = (unsigned short*)w;   w += (size_t)n * 128 * 2;
  unsigned short* xn = (unsigned short*)w;   w += (size_t)n * 128 * 2;
  unsigned short* xd = (unsigned short*)w;
  float* out = (float*)d_out;

  int n4 = n2 / 4;
  int zb = (n4 + 255) / 256;
  pack_zero<<<48 + zb, 256, 0, stream>>>(Wsl, W0, W1, Wg, Wp3, Wgp, (int4*)deg, n4);

  int cd_blocks = (E + 255) / 256;
  int gemm_blocks = (n + 63) / 64;
  count_gemm<<<gemm_blocks + cd_blocks, 256, 0, stream>>>(
      x, Wp3, bsl, hx, h0, h1, col, etype, deg, erank, n, E, gemm_blocks);

  int nb = (n2 + 2047) / 2048;
  scan1<<<nb, 256, 0, stream>>>(deg, partials, n2);
  scan3b<<<nb, 256, 0, stream>>>(partials, deg, row_start, dinv, n2, nb);

  fill_k<<<cd_blocks, 256, 0, stream>>>(row, col, etype, erank, row_start, dinv,
                                        ebuf, n, E);

  int ga_blocks = (int)(((long long)n * 8 + 255) / 256);
  gather2<<<dim3(ga_blocks, 2), 256, 0, stream>>>(h0, h1, ebuf, row_start, deg, dinv,
                                                  b0, b1, xn, xd, n);
  gate_combine<<<(n + 63) / 64, 256, 0, stream>>>(hx, xn, xd, Wgp, bg, out, n);
}